// Round 4
// baseline (99.579 us; speedup 1.0000x reference)
//
#include <hip/hip_runtime.h>
#include <math.h>

#define TPB 256
#define NNEG 2048
#define D 128
#define L2E 1.44269504088896340736f

typedef __attribute__((ext_vector_type(8))) short bf16x8;
typedef __attribute__((ext_vector_type(4))) float f32x4;

#define MFMA16 __builtin_amdgcn_mfma_f32_16x16x32_bf16

static __device__ __forceinline__ unsigned int f2bf(float f) {
    unsigned int u = __float_as_uint(f);
    return (u + 0x7FFFu + ((u >> 16) & 1u)) >> 16;
}

// Opaque register pin: forbids rematerialization/refold of the value's
// producer (e.g. re-reading the fragment from LDS inside the main loop).
static __device__ __forceinline__ void pin(bf16x8& v) {
    asm volatile("" : "+v"(v));
}

// ---------------- prep: normalize negatives -> bf16 [NNEG][D], + log(samp_p) ----------------
__global__ __launch_bounds__(TPB) void sspe_prep(
    const float* __restrict__ embed,
    const float* __restrict__ sprobs,
    const int* __restrict__ sidx,
    unsigned int* __restrict__ en_bf,
    float* __restrict__ ln_samp)
{
    const int t = threadIdx.x;
    const int wave = t >> 6;
    const int lane = t & 63;
    const int j = blockIdx.x * 4 + wave;
    const int idx = sidx[j];

    float2 v = reinterpret_cast<const float2*>(embed)[(size_t)idx * 64 + lane];
    float ss = v.x * v.x + v.y * v.y;
    ss += __shfl_xor(ss, 1);
    ss += __shfl_xor(ss, 2);
    ss += __shfl_xor(ss, 4);
    ss += __shfl_xor(ss, 8);
    ss += __shfl_xor(ss, 16);
    ss += __shfl_xor(ss, 32);
    const float rinv = 1.0f / fmaxf(sqrtf(ss), 1e-12f);
    en_bf[(size_t)j * 64 + lane] = f2bf(v.x * rinv) | (f2bf(v.y * rinv) << 16);
    if (lane == 0) ln_samp[j] = logf(sprobs[idx] + 1e-10f);
}

// ---------------- compute one 16-neg tile: 16 MFMA + epilogue ----------------
static __device__ __forceinline__ void compute_tile(
    const bf16x8 (&A)[4][4], const bf16x8 (&B)[4], const float lk, const int ci,
    const int (&yv)[4][4], float (&l)[4][4], const float t2, const float M2)
{
    f32x4 c[4];
    #pragma unroll
    for (int rt = 0; rt < 4; ++rt) c[rt] = (f32x4){0.f, 0.f, 0.f, 0.f};
    #pragma unroll
    for (int ks = 0; ks < 4; ++ks)
        #pragma unroll
        for (int rt = 0; rt < 4; ++rt)
            c[rt] = MFMA16(A[rt][ks], B[ks], c[rt], 0, 0, 0);
    const float nl2 = fmaf(lk, -L2E, -M2);
    #pragma unroll
    for (int rt = 0; rt < 4; ++rt)
        #pragma unroll
        for (int j = 0; j < 4; ++j) {
            const float a = fmaf(c[rt][j], t2, nl2);
            const float e = __builtin_amdgcn_exp2f(a);
            l[rt][j] += (ci == yv[rt][j]) ? 0.0f : e;
        }
}

#define LOADB(B, LK, CI, it) do {                                  \
    const unsigned char* q_ = pB + (size_t)(it) * 4096;            \
    B[0] = *reinterpret_cast<const bf16x8*>(q_);                   \
    B[1] = *reinterpret_cast<const bf16x8*>(q_ + 64);              \
    B[2] = *reinterpret_cast<const bf16x8*>(q_ + 128);             \
    B[3] = *reinterpret_cast<const bf16x8*>(q_ + 192);             \
    LK = pL[(it) * 16];                                            \
    CI = pI[(it) * 16];                                            \
} while (0)

// ---------------- main: fused normalize + pos + MFMA GEMM + masked sum-exp ----------------
__global__ __launch_bounds__(TPB, 2) void sspe_main(
    const float* __restrict__ hidden,
    const int* __restrict__ y,
    const float* __restrict__ embed,
    const float* __restrict__ sprobs,
    const int* __restrict__ sidx,
    const float* __restrict__ ltemp,
    const unsigned int* __restrict__ en_bf,
    const float* __restrict__ ln_samp,
    float2* __restrict__ partials)
{
    const int t = threadIdx.x;
    const int wave = t >> 6;
    const int lane = t & 63;
    const int rb = blockIdx.x * 64;

    __shared__ __align__(16) unsigned char hs[64 * 256];
    __shared__ float pos_s[64];
    __shared__ int   ys[64];
    __shared__ float sred[4][64];

    const float temp = __builtin_amdgcn_exp2f(fminf(ltemp[0], 4.6f) * L2E);
    const float t2 = temp * L2E;
    const float Mln = temp + 14.0f;         // uniform safe max (|cos|<=1, -log p <= 13.8)
    const float M2 = Mln * L2E;

    if (t < 64) ys[t] = y[rb + t];
    __syncthreads();

    // ---- Prologue: 4 rows per step, gathers batched for MLP ----
    #pragma unroll 1
    for (int i = 0; i < 16; i += 4) {
        float2 h2[4], e2[4];
        int yi[4];
        #pragma unroll
        for (int u = 0; u < 4; ++u) {
            const int lr = wave * 16 + i + u;
            h2[u] = reinterpret_cast<const float2*>(hidden)[(size_t)(rb + lr) * 64 + lane];
            yi[u] = ys[lr];
        }
        #pragma unroll
        for (int u = 0; u < 4; ++u)
            e2[u] = reinterpret_cast<const float2*>(embed)[(size_t)yi[u] * 64 + lane];
        float ss[4], es[4], dt[4];
        #pragma unroll
        for (int u = 0; u < 4; ++u) {
            ss[u] = h2[u].x * h2[u].x + h2[u].y * h2[u].y;
            es[u] = e2[u].x * e2[u].x + e2[u].y * e2[u].y;
            dt[u] = h2[u].x * e2[u].x + h2[u].y * e2[u].y;
        }
        #pragma unroll
        for (int m = 1; m <= 32; m <<= 1)
            #pragma unroll
            for (int u = 0; u < 4; ++u) {
                ss[u] += __shfl_xor(ss[u], m);
                es[u] += __shfl_xor(es[u], m);
                dt[u] += __shfl_xor(dt[u], m);
            }
        #pragma unroll
        for (int u = 0; u < 4; ++u) {
            const int lr = wave * 16 + i + u;
            const float rinv = 1.0f / fmaxf(sqrtf(ss[u]), 1e-12f);
            const unsigned int uu = f2bf(h2[u].x * rinv) | (f2bf(h2[u].y * rinv) << 16);
            const int rx = (lr & 7) << 4;
            *reinterpret_cast<unsigned int*>(hs + lr * 256 + ((lane * 4) ^ rx)) = uu;
            if (lane == 0)
                pos_s[lr] = dt[u] * rinv * (1.0f / fmaxf(sqrtf(es[u]), 1e-12f)) * temp
                            - logf(sprobs[yi[u]] + 1e-10f);
        }
    }
    __syncthreads();

    // ---- A fragments from swizzled LDS: read ONCE, pin resident ----
    bf16x8 A[4][4];
    #pragma unroll
    for (int rt = 0; rt < 4; ++rt) {
        const int row = rt * 16 + (lane & 15);
        const int rx = (row & 7) << 4;
        const unsigned char* rp = hs + row * 256;
        #pragma unroll
        for (int ks = 0; ks < 4; ++ks) {
            const int col = ((ks * 64) + ((lane >> 4) << 4)) ^ rx;
            A[rt][ks] = *reinterpret_cast<const bf16x8*>(rp + col);
            pin(A[rt][ks]);
        }
    }

    int yv[4][4];
    float l[4][4];
    #pragma unroll
    for (int rt = 0; rt < 4; ++rt)
        #pragma unroll
        for (int j = 0; j < 4; ++j) {
            yv[rt][j] = ys[rt * 16 + ((lane >> 4) << 2) + j];
            l[rt][j] = 0.0f;
        }

    // ---- Main loop: software-pipelined, 2 tiles per iteration ----
    const int nw = wave * 512;
    const unsigned char* pB = reinterpret_cast<const unsigned char*>(en_bf)
                            + (size_t)(nw + (lane & 15)) * 256 + ((lane >> 4) << 4);
    const float* pL = ln_samp + nw + (lane & 15);
    const int* pI = sidx + nw + (lane & 15);

    bf16x8 B0[4], B1[4];
    float lk0, lk1;
    int ci0, ci1;

    LOADB(B0, lk0, ci0, 0);
    #pragma unroll 1
    for (int nb = 0; nb < 30; nb += 2) {
        LOADB(B1, lk1, ci1, nb + 1);
        compute_tile(A, B0, lk0, ci0, yv, l, t2, M2);
        LOADB(B0, lk0, ci0, nb + 2);
        compute_tile(A, B1, lk1, ci1, yv, l, t2, M2);
    }
    LOADB(B1, lk1, ci1, 31);
    compute_tile(A, B0, lk0, ci0, yv, l, t2, M2);
    compute_tile(A, B1, lk1, ci1, yv, l, t2, M2);

    // ---- Reduce l across the 4 column-groups ----
    #pragma unroll
    for (int rt = 0; rt < 4; ++rt)
        #pragma unroll
        for (int j = 0; j < 4; ++j) {
            float v = l[rt][j];
            v += __shfl_xor(v, 1);
            v += __shfl_xor(v, 2);
            v += __shfl_xor(v, 4);
            v += __shfl_xor(v, 8);
            l[rt][j] = v;
        }
    if ((lane & 15) == 0) {
        #pragma unroll
        for (int rt = 0; rt < 4; ++rt)
            #pragma unroll
            for (int j = 0; j < 4; ++j)
                sred[wave][rt * 16 + ((lane >> 4) << 2) + j] = l[rt][j];
    }
    __syncthreads();

    // ---- Per-row loss + block reduce ----
    if (t < 64) {
        const float s = sred[0][t] + sred[1][t] + sred[2][t] + sred[3][t];
        const float pa = pos_s[t];
        const float stot = s + __builtin_amdgcn_exp2f(fmaf(pa, L2E, -M2));
        float per = Mln + logf(stot) - pa;
        float w = (ys[t] != 0) ? 1.0f : 0.0f;
        per *= w;
        #pragma unroll
        for (int msk = 1; msk < 64; msk <<= 1) {
            per += __shfl_xor(per, msk);
            w += __shfl_xor(w, msk);
        }
        if (t == 0) partials[blockIdx.x] = make_float2(per, w);
    }
}

// ---------------- finalize: deterministic reduction ----------------
__global__ __launch_bounds__(TPB) void sspe_finalize(
    const float2* __restrict__ partials, int n, float* __restrict__ out)
{
    __shared__ float ssum[TPB];
    __shared__ float scnt[TPB];
    const int t = threadIdx.x;
    float s = 0.0f, c = 0.0f;
    for (int i = t; i < n; i += TPB) {
        const float2 p = partials[i];
        s += p.x; c += p.y;
    }
    ssum[t] = s; scnt[t] = c;
    __syncthreads();
    for (int k = TPB / 2; k > 0; k >>= 1) {
        if (t < k) { ssum[t] += ssum[t + k]; scnt[t] += scnt[t + k]; }
        __syncthreads();
    }
    if (t == 0) out[0] = ssum[0] / fmaxf(scnt[0], 1.0f);
}

extern "C" void kernel_launch(void* const* d_in, const int* in_sizes, int n_in,
                              void* d_out, int out_size, void* d_ws, size_t ws_size,
                              hipStream_t stream) {
    const float* hidden = (const float*)d_in[0];
    const int*   yv     = (const int*)d_in[1];
    const float* embed  = (const float*)d_in[2];
    const float* sprobs = (const float*)d_in[3];
    const int*   sidx   = (const int*)d_in[4];
    const float* ltemp  = (const float*)d_in[5];
    float* out = (float*)d_out;

    const int nrows = in_sizes[1];
    const int nblocks = nrows / 64;

    char* w = (char*)d_ws;
    unsigned int* en_bf  = (unsigned int*)w;
    float*  ln_samp      = (float*)(w + (size_t)NNEG * D * 2);
    float2* partials     = (float2*)(w + (size_t)NNEG * D * 2 + NNEG * 4);

    sspe_prep<<<NNEG / 4, TPB, 0, stream>>>(embed, sprobs, sidx, en_bf, ln_samp);
    sspe_main<<<nblocks, TPB, 0, stream>>>(hidden, yv, embed, sprobs, sidx, ltemp,
                                           en_bf, ln_samp, partials);
    sspe_finalize<<<1, TPB, 0, stream>>>(partials, nblocks, out);
}

// Round 5
// 80.526 us; speedup vs baseline: 1.2366x; 1.2366x over previous
//
#include <hip/hip_runtime.h>
#include <math.h>

#define TPB 256
#define NNEG 2048
#define D 128
#define CHUNK 64
#define NCH (NNEG / CHUNK)
#define L2E 1.44269504088896340736f

typedef __attribute__((ext_vector_type(8))) short bf16x8;
typedef __attribute__((ext_vector_type(4))) float f32x4;

#define MFMA16 __builtin_amdgcn_mfma_f32_16x16x32_bf16

static __device__ __forceinline__ unsigned int f2bf(float f) {
    unsigned int u = __float_as_uint(f);
    return (u + 0x7FFFu + ((u >> 16) & 1u)) >> 16;
}

// async global->LDS, 16B per lane; LDS dest is wave-uniform base + lane*16
static __device__ __forceinline__ void stage16(const void* g, void* l) {
    __builtin_amdgcn_global_load_lds(
        (const __attribute__((address_space(1))) unsigned int*)g,
        (__attribute__((address_space(3))) unsigned int*)l, 16, 0, 0);
}

// ---------------- prep: normalize negatives -> bf16 [NNEG][D], + log(samp_p) ----------------
__global__ __launch_bounds__(TPB) void sspe_prep(
    const float* __restrict__ embed,
    const float* __restrict__ sprobs,
    const int* __restrict__ sidx,
    unsigned int* __restrict__ en_bf,
    float* __restrict__ ln_samp)
{
    const int t = threadIdx.x;
    const int wave = t >> 6;
    const int lane = t & 63;
    const int j = blockIdx.x * 4 + wave;
    const int idx = sidx[j];

    float2 v = reinterpret_cast<const float2*>(embed)[(size_t)idx * 64 + lane];
    float ss = v.x * v.x + v.y * v.y;
    ss += __shfl_xor(ss, 1);
    ss += __shfl_xor(ss, 2);
    ss += __shfl_xor(ss, 4);
    ss += __shfl_xor(ss, 8);
    ss += __shfl_xor(ss, 16);
    ss += __shfl_xor(ss, 32);
    const float rinv = 1.0f / fmaxf(sqrtf(ss), 1e-12f);
    en_bf[(size_t)j * 64 + lane] = f2bf(v.x * rinv) | (f2bf(v.y * rinv) << 16);
    if (lane == 0) ln_samp[j] = logf(sprobs[idx] + 1e-10f);
}

// ---------------- main ----------------
__global__ __launch_bounds__(TPB, 4) void sspe_main(
    const float* __restrict__ hidden,
    const int* __restrict__ y,
    const float* __restrict__ embed,
    const float* __restrict__ sprobs,
    const int* __restrict__ sidx,
    const float* __restrict__ ltemp,
    const unsigned int* __restrict__ en_bf,
    const float* __restrict__ ln_samp,
    float2* __restrict__ partials)
{
    const int t = threadIdx.x;
    const int wave = t >> 6;
    const int lane = t & 63;
    const int rb = blockIdx.x * 64;

    // 32 KB: two 16 KB B-buffers; buffer 0 doubles as the hidden-tile (hs)
    // region during the prologue (hs is dead once A-fragments are loaded).
    __shared__ __align__(16) unsigned char smem[2 * CHUNK * 256];
    __shared__ float pos_s[64];
    __shared__ int   ys[64];
    __shared__ float sums[64];

    const float temp = __builtin_amdgcn_exp2f(fminf(ltemp[0], 4.6f) * L2E);
    const float t2 = temp * L2E;
    const float Mln = temp + 14.0f;      // uniform safe max (|cos|<=1, -log p <= 13.8)
    const float M2 = Mln * L2E;

    if (t < 64) ys[t] = y[rb + t];
    __syncthreads();

    // ---- Prologue: normalize 16 rows/wave -> bf16 into smem[0..16K) (swizzled) ----
    #pragma unroll 1
    for (int i = 0; i < 16; i += 4) {
        float2 h2[4], e2[4];
        int yi[4];
        #pragma unroll
        for (int u = 0; u < 4; ++u) {
            const int lr = wave * 16 + i + u;
            h2[u] = reinterpret_cast<const float2*>(hidden)[(size_t)(rb + lr) * 64 + lane];
            yi[u] = ys[lr];
        }
        #pragma unroll
        for (int u = 0; u < 4; ++u)
            e2[u] = reinterpret_cast<const float2*>(embed)[(size_t)yi[u] * 64 + lane];
        float ss[4], es[4], dt[4];
        #pragma unroll
        for (int u = 0; u < 4; ++u) {
            ss[u] = h2[u].x * h2[u].x + h2[u].y * h2[u].y;
            es[u] = e2[u].x * e2[u].x + e2[u].y * e2[u].y;
            dt[u] = h2[u].x * e2[u].x + h2[u].y * e2[u].y;
        }
        #pragma unroll
        for (int m = 1; m <= 32; m <<= 1)
            #pragma unroll
            for (int u = 0; u < 4; ++u) {
                ss[u] += __shfl_xor(ss[u], m);
                es[u] += __shfl_xor(es[u], m);
                dt[u] += __shfl_xor(dt[u], m);
            }
        #pragma unroll
        for (int u = 0; u < 4; ++u) {
            const int lr = wave * 16 + i + u;
            const float rinv = 1.0f / fmaxf(sqrtf(ss[u]), 1e-12f);
            const unsigned int uu = f2bf(h2[u].x * rinv) | (f2bf(h2[u].y * rinv) << 16);
            const int rx = (lr & 7) << 4;
            *reinterpret_cast<unsigned int*>(smem + lr * 256 + ((lane * 4) ^ rx)) = uu;
            if (lane == 0)
                pos_s[lr] = dt[u] * rinv * (1.0f / fmaxf(sqrtf(es[u]), 1e-12f)) * temp
                            - logf(sprobs[yi[u]] + 1e-10f);
        }
    }
    __syncthreads();

    // ---- A fragments: this wave's 16 rows (row = wave*16 + (lane&15)) ----
    bf16x8 A[4];
    {
        const int row = wave * 16 + (lane & 15);
        const int rx = (lane & 7) << 4;
        const unsigned char* rp = smem + row * 256;
        #pragma unroll
        for (int ks = 0; ks < 4; ++ks)
            A[ks] = *reinterpret_cast<const bf16x8*>(
                rp + ((ks * 64 + ((lane >> 4) << 4)) ^ rx));
    }
    __syncthreads();   // everyone done reading smem[0..16K) before restaging

    const int cj = lane & 15;       // neg-in-tile (C/D col)
    const int rgrp = lane >> 4;     // row group  (C/D rows rgrp*4..+4)
    int yv[4];
    float l[4];
    #pragma unroll
    for (int j = 0; j < 4; ++j) {
        yv[j] = ys[wave * 16 + rgrp * 4 + j];
        l[j] = 0.0f;
    }

    // per-lane swizzled source offsets for staging (involution of read swizzle)
    unsigned int soff[4];
    #pragma unroll
    for (int i = 0; i < 4; ++i) {
        const unsigned int doff = i * 4096 + wave * 1024 + lane * 16;
        soff[i] = doff ^ (((doff >> 8) & 7) << 4);
    }
    const unsigned char* en = reinterpret_cast<const unsigned char*>(en_bf);
    const int rx = (cj & 7) << 4;

    // stage chunk 0 -> buffer 0
    #pragma unroll
    for (int i = 0; i < 4; ++i)
        stage16(en + soff[i], smem + i * 4096 + wave * 1024);

    // ---- Main loop: 32 chunks of 64 negs, double-buffered, 1 barrier/chunk ----
    #pragma unroll 1
    for (int ch = 0; ch < NCH; ++ch) {
        const int cur = (ch & 1) << 14;
        const int nxt = cur ^ 16384;
        __syncthreads();   // compiler drains own vmcnt (stage ch) + lgkm here

        // lk/ci for this chunk (issued BEFORE next stage so their waits
        // don't drain the staging queue)
        float lk[4];
        int ci[4];
        #pragma unroll
        for (int tt = 0; tt < 4; ++tt) {
            lk[tt] = ln_samp[ch * 64 + tt * 16 + cj];
            ci[tt] = sidx[ch * 64 + tt * 16 + cj];
        }

        if (ch + 1 < NCH) {
            const unsigned char* enn = en + (size_t)(ch + 1) * 16384;
            #pragma unroll
            for (int i = 0; i < 4; ++i)
                stage16(enn + soff[i], smem + nxt + i * 4096 + wave * 1024);
        }

        // 4 tiles x 4 k-steps from LDS, 4 independent MFMA chains
        f32x4 c[4];
        #pragma unroll
        for (int tt = 0; tt < 4; ++tt) {
            const unsigned char* bp = smem + cur + (tt * 16 + cj) * 256;
            c[tt] = (f32x4){0.f, 0.f, 0.f, 0.f};
            #pragma unroll
            for (int ks = 0; ks < 4; ++ks) {
                const bf16x8 b = *reinterpret_cast<const bf16x8*>(
                    bp + ((ks * 64 + (rgrp << 4)) ^ rx));
                c[tt] = MFMA16(A[ks], b, c[tt], 0, 0, 0);
            }
        }

        // epilogue: adjust, mask collisions, accumulate exp
        #pragma unroll
        for (int tt = 0; tt < 4; ++tt) {
            const float nl2 = fmaf(lk[tt], -L2E, -M2);
            #pragma unroll
            for (int j = 0; j < 4; ++j) {
                const float a = fmaf(c[tt][j], t2, nl2);
                const float e = __builtin_amdgcn_exp2f(a);
                l[j] += (ci[tt] == yv[j]) ? 0.0f : e;
            }
        }
    }

    // ---- Reduce across the 16 neg-columns (lanes sharing rgrp) ----
    #pragma unroll
    for (int j = 0; j < 4; ++j) {
        float v = l[j];
        v += __shfl_xor(v, 1);
        v += __shfl_xor(v, 2);
        v += __shfl_xor(v, 4);
        v += __shfl_xor(v, 8);
        l[j] = v;
    }
    if (cj == 0) {
        #pragma unroll
        for (int j = 0; j < 4; ++j)
            sums[wave * 16 + rgrp * 4 + j] = l[j];
    }
    __syncthreads();

    // ---- Per-row loss + block reduce ----
    if (t < 64) {
        const float s = sums[t];
        const float pa = pos_s[t];
        const float stot = s + __builtin_amdgcn_exp2f(fmaf(pa, L2E, -M2));
        float per = Mln + logf(stot) - pa;
        float w = (ys[t] != 0) ? 1.0f : 0.0f;
        per *= w;
        #pragma unroll
        for (int msk = 1; msk < 64; msk <<= 1) {
            per += __shfl_xor(per, msk);
            w += __shfl_xor(w, msk);
        }
        if (t == 0) partials[blockIdx.x] = make_float2(per, w);
    }
}

// ---------------- finalize: deterministic reduction ----------------
__global__ __launch_bounds__(TPB) void sspe_finalize(
    const float2* __restrict__ partials, int n, float* __restrict__ out)
{
    __shared__ float ssum[TPB];
    __shared__ float scnt[TPB];
    const int t = threadIdx.x;
    float s = 0.0f, c = 0.0f;
    for (int i = t; i < n; i += TPB) {
        const float2 p = partials[i];
        s += p.x; c += p.y;
    }
    ssum[t] = s; scnt[t] = c;
    __syncthreads();
    for (int k = TPB / 2; k > 0; k >>= 1) {
        if (t < k) { ssum[t] += ssum[t + k]; scnt[t] += scnt[t + k]; }
        __syncthreads();
    }
    if (t == 0) out[0] = ssum[0] / fmaxf(scnt[0], 1.0f);
}

extern "C" void kernel_launch(void* const* d_in, const int* in_sizes, int n_in,
                              void* d_out, int out_size, void* d_ws, size_t ws_size,
                              hipStream_t stream) {
    const float* hidden = (const float*)d_in[0];
    const int*   yv     = (const int*)d_in[1];
    const float* embed  = (const float*)d_in[2];
    const float* sprobs = (const float*)d_in[3];
    const int*   sidx   = (const int*)d_in[4];
    const float* ltemp  = (const float*)d_in[5];
    float* out = (float*)d_out;

    const int nrows = in_sizes[1];
    const int nblocks = nrows / 64;

    char* w = (char*)d_ws;
    unsigned int* en_bf  = (unsigned int*)w;
    float*  ln_samp      = (float*)(w + (size_t)NNEG * D * 2);
    float2* partials     = (float2*)(w + (size_t)NNEG * D * 2 + NNEG * 4);

    sspe_prep<<<NNEG / 4, TPB, 0, stream>>>(embed, sprobs, sidx, en_bf, ln_samp);
    sspe_main<<<nblocks, TPB, 0, stream>>>(hidden, yv, embed, sprobs, sidx, ltemp,
                                           en_bf, ln_samp, partials);
    sspe_finalize<<<1, TPB, 0, stream>>>(partials, nblocks, out);
}